// Round 14
// baseline (276.102 us; speedup 1.0000x reference)
//
#include <hip/hip_runtime.h>
#include <hip/hip_bf16.h>
#include <math.h>

// GCN stack: 3x [GCNConv + ReLU] + MLP head (64->32 relu ->40) + log_softmax.
// R28: base = R27 (273.7us). Single change: edge_scatter grid widened.
// It had the same disease R27 cured in bucket_csr: 196 blocks (<1/CU),
// latency-exposed. ESH 13->11: 2048-edge tiles -> 782 blocks (~3/CU),
// 512 threads, LDS staging 40KB->10KB. Same algorithm/ebuf layout/numerics;
// gcursor atomics 4x on a 784B L2-resident array (noise).
// Gathers remain at the measured line-service floor (R20/R23: only distinct
// random 128B line count matters, = E + n, algorithmically fixed).

#define DIMF 64
#define BSH  9       // 512 nodes per bucket
#define ESH  11      // 2048 edges per scatter block
#define ECAP 16320   // fixed ebuf capacity per bucket (196*16320*4 <= hpB)
#define LSCAP 10240  // bucket_csr LDS staging capacity (40 KB)

static __device__ __forceinline__ unsigned short f2bf(float f)
{
    __hip_bfloat16 b = __float2bfloat16(f);
    return *(unsigned short*)&b;
}

// ---------------- CSR build: fused scatter ----------------

__global__ __launch_bounds__(512) void edge_scatter(
    const int* __restrict__ src, const int* __restrict__ dst,
    int* __restrict__ gcursor, unsigned int* __restrict__ ebuf, int E)
{
    __shared__ unsigned int  pk[2048];   // 8 KB packed (src<<9)|(dst&511)
    __shared__ unsigned char bk[2048];   // 2 KB bucket id (<=195)
    __shared__ int hcnt[256];
    __shared__ int hbase[256];
    int t = threadIdx.x;
    if (t < 256) hcnt[t] = 0;
    __syncthreads();
    int e0 = blockIdx.x << ESH;
    int e1 = min(E, e0 + 2048);
    int m = e1 - e0;
    for (int i = t; i < m; i += 512) {
        int d = dst[e0 + i];
        int s = src[e0 + i];
        int b = d >> BSH;
        pk[i] = ((unsigned int)s << BSH) | (unsigned int)(d & 511);
        bk[i] = (unsigned char)b;
        atomicAdd(&hcnt[b], 1);
    }
    __syncthreads();
    if (t < 256) {
        hbase[t] = hcnt[t] ? atomicAdd(&gcursor[t], hcnt[t]) : 0;
        hcnt[t] = 0;
    }
    __syncthreads();
    for (int i = t; i < m; i += 512) {
        int b = bk[i];
        int p = hbase[b] + atomicAdd(&hcnt[b], 1);
        ebuf[(size_t)b * ECAP + p] = pk[i];
    }
}

// ---------------- bucket_csr: 512 thr, LDS-staged compact list ----------

__global__ __launch_bounds__(512) void bucket_csr(
    const unsigned int* __restrict__ ebuf, const int* __restrict__ gcursor,
    int* __restrict__ row_start, int* __restrict__ csr_src,
    float* __restrict__ dinv, int n, int E)
{
    __shared__ int cnt[512];     // 2 KB: per-node count -> scan -> cursor
    __shared__ int ps[256];      // 1 KB: bucket-prefix scan
    __shared__ int ls[LSCAP];    // 40 KB: compact src staging
    int t = threadIdx.x;
    int blk = blockIdx.x;
    int node0 = blk << BSH;
    int nbk = gridDim.x;

    // exclusive prefix of bucket counts (first 256 threads; nbk <= 256)
    if (t < 256) ps[t] = (t < nbk) ? gcursor[t] : 0;
    __syncthreads();
    for (int off = 1; off < 256; off <<= 1) {
        int v = 0;
        if (t < 256 && t >= off) v = ps[t - off];
        __syncthreads();
        if (t < 256) ps[t] += v;
        __syncthreads();
    }
    int bs   = ps[blk] - gcursor[blk];   // global base of this bucket
    int bcnt = gcursor[blk];             // edges in this bucket

    // per-node histogram
    cnt[t] = 0;
    __syncthreads();
    size_t base = (size_t)blk * ECAP;
    for (int i = t; i < bcnt; i += 512)
        atomicAdd(&cnt[ebuf[base + i] & 511], 1);
    __syncthreads();
    int myc = cnt[t];
    __syncthreads();
    // inclusive scan over 512 node counts (512 threads, Hillis-Steele)
    for (int off = 1; off < 512; off <<= 1) {
        int v = (t >= off) ? cnt[t - off] : 0;
        __syncthreads();
        cnt[t] += v;
        __syncthreads();
    }
    int excl = cnt[t] - myc;
    int g = node0 + t;
    if (g < n) { row_start[g] = bs + excl; dinv[g] = rsqrtf((float)myc + 1.0f); }
    __syncthreads();
    cnt[t] = excl;                       // becomes local cursor
    __syncthreads();

    if (bcnt <= LSCAP) {
        // scatter into LDS staging (random 4B writes stay on-chip)
        for (int i = t; i < bcnt; i += 512) {
            unsigned int pkv = ebuf[base + i];
            int p = atomicAdd(&cnt[pkv & 511], 1);
            ls[p] = (int)(pkv >> BSH);
        }
        __syncthreads();
        // coalesced stream-out
        for (int i = t; i < bcnt; i += 512)
            csr_src[bs + i] = ls[i];
    } else {
        // fallback (statistically unreachable): direct global scatter
        for (int i = t; i < bcnt; i += 512) {
            unsigned int pkv = ebuf[base + i];
            int p = bs + atomicAdd(&cnt[pkv & 511], 1);
            csr_src[p] = (int)(pkv >> BSH);
        }
    }
    if (blk == gridDim.x - 1 && t == 0) row_start[n] = E;
}

// ---------------- shared register-blocked gemm body ----------------

#define GEMM_RB(ACC0, ACC1, XS, WS)                                        \
    float ACC0[4] = {0.f, 0.f, 0.f, 0.f};                                  \
    float ACC1[4] = {0.f, 0.f, 0.f, 0.f};                                  \
    {                                                                      \
        int cg4 = (t & 15) << 2;                                           \
        int rr0 = (t >> 4) << 1;                                           \
        _Pragma("unroll 4")                                                \
        for (int k = 0; k < 64; k++) {                                     \
            float4 w = *(const float4*)&WS[(k << 6) + cg4];                \
            float x0 = XS[rr0][k];                                         \
            float x1 = XS[rr0 + 1][k];                                     \
            ACC0[0] = fmaf(x0, w.x, ACC0[0]);                              \
            ACC0[1] = fmaf(x0, w.y, ACC0[1]);                              \
            ACC0[2] = fmaf(x0, w.z, ACC0[2]);                              \
            ACC0[3] = fmaf(x0, w.w, ACC0[3]);                              \
            ACC1[0] = fmaf(x1, w.x, ACC1[0]);                              \
            ACC1[1] = fmaf(x1, w.y, ACC1[1]);                              \
            ACC1[2] = fmaf(x1, w.z, ACC1[2]);                              \
            ACC1[3] = fmaf(x1, w.w, ACC1[3]);                              \
        }                                                                  \
    }

#define GEMM_STORE(ACC, GR)                                                \
    if ((GR) < n) {                                                        \
        float dv = dinv[GR];                                               \
        ushort4 u;                                                         \
        u.x = f2bf(ACC[0] * dv);                                           \
        u.y = f2bf(ACC[1] * dv);                                           \
        u.z = f2bf(ACC[2] * dv);                                           \
        u.w = f2bf(ACC[3] * dv);                                           \
        *(ushort4*)(hpout + (size_t)(GR) * DIMF + ((t & 15) << 2)) = u;    \
    }

// Write the zero row at hp[n] (gather clamps out-of-degree slots here).
#define ZERO_ROW(HP)                                                       \
    if (blockIdx.x == 0 && t < 32)                                         \
        ((unsigned int*)(HP))[(size_t)n * 32 + t] = 0u;

// ---------------- K0: gemm0 (f32 x -> hpA bf16), 256 threads ----------

__global__ __launch_bounds__(256) void gemm_scale_f32(
    const float* __restrict__ xin, const float* __restrict__ W,
    const float* __restrict__ dinv, __hip_bfloat16* __restrict__ hpout, int n)
{
    __shared__ float Ws[64 * 64];
    __shared__ float Xs[32][65];
    int t = threadIdx.x;
    ZERO_ROW(hpout)
    {
        const float4* Wv = (const float4*)W;
        float4* Wsv = (float4*)Ws;
        for (int i = t; i < 1024; i += 256) Wsv[i] = Wv[i];
    }
    int row0 = blockIdx.x * 32;
    for (int i = t; i < 512; i += 256) {
        int r = i >> 4, c4 = (i & 15) << 2;
        int gr = row0 + r;
        float4 v = {0.f, 0.f, 0.f, 0.f};
        if (gr < n) v = *(const float4*)(xin + (size_t)gr * DIMF + c4);
        Xs[r][c4]     = v.x;
        Xs[r][c4 + 1] = v.y;
        Xs[r][c4 + 2] = v.z;
        Xs[r][c4 + 3] = v.w;
    }
    __syncthreads();

    GEMM_RB(acc0, acc1, Xs, Ws)
    int gr0 = row0 + ((t >> 4) << 1);
    GEMM_STORE(acc0, gr0)
    GEMM_STORE(acc1, gr0 + 1)
}

// ---------------- shared gather body (8-deep, vectorized indices) --------
// Lane o of each 8-lane group loads ONE index csr_src[rs+k+o] (clamped to
// the zero row n for slots >= deg); __shfl within the group broadcasts the
// 8 indices for the 8 row loads. Row j -> a[j%4] striping preserved.

#define ADDROW(a, v)                                                       \
    {                                                                      \
        a[0] += __uint_as_float((v).x << 16);                              \
        a[1] += __uint_as_float((v).x & 0xffff0000u);                      \
        a[2] += __uint_as_float((v).y << 16);                              \
        a[3] += __uint_as_float((v).y & 0xffff0000u);                      \
        a[4] += __uint_as_float((v).z << 16);                              \
        a[5] += __uint_as_float((v).z & 0xffff0000u);                      \
        a[6] += __uint_as_float((v).w << 16);                              \
        a[7] += __uint_as_float((v).w & 0xffff0000u);                      \
    }

#define GATHER_BODY(xv_out)                                                    \
    float xv_out[8];                                                           \
    {                                                                          \
        int rs = row_start[node];                                              \
        int deg = row_start[node + 1] - rs;                                    \
        float a0[8], a1[8], a2[8], a3[8];                                      \
        _Pragma("unroll")                                                      \
        for (int i = 0; i < 8; i++) { a0[i]=0.f; a1[i]=0.f; a2[i]=0.f; a3[i]=0.f; } \
        {                                                                      \
            uint4 v = *(const uint4*)(hprime + (size_t)node * 32 + uoff);      \
            ADDROW(a0, v);                                                     \
        }                                                                      \
        int gb = lane & ~7;            /* group base lane in wave */           \
        int idxv;                                                              \
        {                                                                      \
            int _c = csr_src[rs + o];                                          \
            idxv = (o < deg) ? _c : n;                                         \
        }                                                                      \
        for (int k = 0; k < deg; k += 8) {                                     \
            int i0 = __shfl(idxv, gb + 0, 64);                                 \
            int i1 = __shfl(idxv, gb + 1, 64);                                 \
            int i2 = __shfl(idxv, gb + 2, 64);                                 \
            int i3 = __shfl(idxv, gb + 3, 64);                                 \
            int i4 = __shfl(idxv, gb + 4, 64);                                 \
            int i5 = __shfl(idxv, gb + 5, 64);                                 \
            int i6 = __shfl(idxv, gb + 6, 64);                                 \
            int i7 = __shfl(idxv, gb + 7, 64);                                 \
            int kn = k + 8;                                                    \
            int _c = csr_src[rs + kn + o];                                     \
            int nidx = (kn + o < deg) ? _c : n;                                \
            uint4 v0 = *(const uint4*)(hprime + (size_t)i0 * 32 + uoff);       \
            uint4 v1 = *(const uint4*)(hprime + (size_t)i1 * 32 + uoff);       \
            uint4 v2 = *(const uint4*)(hprime + (size_t)i2 * 32 + uoff);       \
            uint4 v3 = *(const uint4*)(hprime + (size_t)i3 * 32 + uoff);       \
            uint4 v4 = *(const uint4*)(hprime + (size_t)i4 * 32 + uoff);       \
            uint4 v5 = *(const uint4*)(hprime + (size_t)i5 * 32 + uoff);       \
            uint4 v6 = *(const uint4*)(hprime + (size_t)i6 * 32 + uoff);       \
            uint4 v7 = *(const uint4*)(hprime + (size_t)i7 * 32 + uoff);       \
            ADDROW(a0, v0); ADDROW(a1, v1); ADDROW(a2, v2); ADDROW(a3, v3);    \
            ADDROW(a0, v4); ADDROW(a1, v5); ADDROW(a2, v6); ADDROW(a3, v7);    \
            idxv = nidx;                                                       \
        }                                                                      \
        int f8 = uoff << 1;                                                    \
        float dv = dinv[node];                                                 \
        _Pragma("unroll")                                                      \
        for (int j = 0; j < 8; j++)                                            \
            xv_out[j] = fmaxf(fmaf(dv, a0[j] + a1[j] + a2[j] + a3[j],          \
                                   b[f8 + j]), 0.0f);                          \
    }

// ---------------- K1/K2: gather(l) + gemm(l+1), 512 thr / 64 nodes -------

__global__ __launch_bounds__(512) void gather_gemm(
    const unsigned int* __restrict__ hprime,  // hp(l) bf16x2, 32 uints/row
    const int* __restrict__ row_start, const int* __restrict__ csr_src,
    const float* __restrict__ dinv, const float* __restrict__ b,   // b(l)
    const float* __restrict__ Wn,                                  // W(l+1)
    __hip_bfloat16* __restrict__ hpout, int n)
{
    __shared__ float Ws[64 * 64];   // 16 KB
    __shared__ float Xs[64][65];    // 16.6 KB
    int t = threadIdx.x;
    ZERO_ROW(hpout)
    {
        const float4* Wv = (const float4*)Wn;
        float4* Wsv = (float4*)Ws;
        for (int i = t; i < 1024; i += 512) Wsv[i] = Wv[i];
    }

    int wave = t >> 6;
    int lane = t & 63;
    int slot = lane >> 3;
    int o    = lane & 7;
    int uoff = o << 2;
    int ln   = (wave << 3) + slot;          // local node 0..63
    int row0 = blockIdx.x * 64;
    int node = row0 + ln;
    int f8l  = o << 3;

    if (node < n) {
        GATHER_BODY(xv)
#pragma unroll
        for (int j = 0; j < 8; j++) Xs[ln][f8l + j] = xv[j];
    } else {
#pragma unroll
        for (int j = 0; j < 8; j++) Xs[ln][f8l + j] = 0.0f;
    }
    __syncthreads();

    GEMM_RB(acc0, acc1, Xs, Ws)
    int gr0 = row0 + ((t >> 4) << 1);
    GEMM_STORE(acc0, gr0)
    GEMM_STORE(acc1, gr0 + 1)
}

// ---------------- K3: gather(2) + MLP head, 512 thr / 64 nodes ----------

__global__ __launch_bounds__(512) void gather_head(
    const unsigned int* __restrict__ hprime,  // hp(2) bf16x2
    const int* __restrict__ row_start, const int* __restrict__ csr_src,
    const float* __restrict__ dinv, const float* __restrict__ b,   // b(2)
    const float* __restrict__ Wp1, const float* __restrict__ bp1,
    const float* __restrict__ Wp2, const float* __restrict__ bp2,
    float* __restrict__ out, int n)
{
    __shared__ float W1s[64 * 32];   // 8 KB
    __shared__ float W2t[40][36];    // 5.76 KB, transposed + padded
    __shared__ float b1s[32], b2s[40];
    __shared__ float Xs[64][65];     // 16.6 KB
    __shared__ float Hs[64][33];     // 8.4 KB
    int t = threadIdx.x;
    {
        const float4* Wv = (const float4*)Wp1;
        float4* Wsv = (float4*)W1s;
        for (int i = t; i < 512; i += 512) Wsv[i] = Wv[i];
    }
    for (int i = t; i < 1280; i += 512) {
        int k = i & 31, j = i >> 5;
        W2t[j][k] = Wp2[k * 40 + j];
    }
    if (t < 32) b1s[t] = bp1[t];
    if (t < 40) b2s[t] = bp2[t];

    int wave = t >> 6;
    int lane = t & 63;
    int slot = lane >> 3;
    int o    = lane & 7;
    int uoff = o << 2;
    int ln   = (wave << 3) + slot;          // local node 0..63
    int node = blockIdx.x * 64 + ln;
    int f8l  = o << 3;

    if (node < n) {
        GATHER_BODY(xv)
#pragma unroll
        for (int j = 0; j < 8; j++) Xs[ln][f8l + j] = xv[j];
    } else {
#pragma unroll
        for (int j = 0; j < 8; j++) Xs[ln][f8l + j] = 0.0f;
    }
    __syncthreads();   // Xs complete + weights staged

    // lane computes h channels o*4 .. o*4+3 over all 64 inputs
    float h[4];
#pragma unroll
    for (int m = 0; m < 4; m++) h[m] = b1s[o * 4 + m];
#pragma unroll 4
    for (int k = 0; k < 64; k++) {
        float xk = Xs[ln][k];
        float4 w = *(const float4*)&W1s[(k << 5) + (o << 2)];
        h[0] = fmaf(xk, w.x, h[0]);
        h[1] = fmaf(xk, w.y, h[1]);
        h[2] = fmaf(xk, w.z, h[2]);
        h[3] = fmaf(xk, w.w, h[3]);
    }
#pragma unroll
    for (int m = 0; m < 4; m++) Hs[ln][o * 4 + m] = fmaxf(h[m], 0.0f);
    // Hs written/read by the same wave: no __syncthreads needed

    if (node < n) {
        float oo[5];
#pragma unroll
        for (int m = 0; m < 5; m++) oo[m] = b2s[o * 5 + m];
#pragma unroll
        for (int k4 = 0; k4 < 8; k4++) {
            float hk0 = Hs[ln][4 * k4 + 0];
            float hk1 = Hs[ln][4 * k4 + 1];
            float hk2 = Hs[ln][4 * k4 + 2];
            float hk3 = Hs[ln][4 * k4 + 3];
#pragma unroll
            for (int m = 0; m < 5; m++) {
                float4 w = *(const float4*)&W2t[o * 5 + m][4 * k4];
                oo[m] = fmaf(hk3, w.w, fmaf(hk2, w.z,
                         fmaf(hk1, w.y, fmaf(hk0, w.x, oo[m]))));
            }
        }
        float mx = oo[0];
#pragma unroll
        for (int m = 1; m < 5; m++) mx = fmaxf(mx, oo[m]);
#pragma unroll
        for (int mask = 1; mask <= 4; mask <<= 1) mx = fmaxf(mx, __shfl_xor(mx, mask));
        float se = 0.0f;
#pragma unroll
        for (int m = 0; m < 5; m++) se += expf(oo[m] - mx);
#pragma unroll
        for (int mask = 1; mask <= 4; mask <<= 1) se += __shfl_xor(se, mask);
        float lse = logf(se) + mx;
        float* op = out + (size_t)node * 40 + o * 5;
#pragma unroll
        for (int m = 0; m < 5; m++) op[m] = oo[m] - lse;
    }
}

extern "C" void kernel_launch(void* const* d_in, const int* in_sizes, int n_in,
                              void* d_out, int out_size, void* d_ws, size_t ws_size,
                              hipStream_t stream)
{
    const float* x  = (const float*)d_in[0];
    const int*   ei = (const int*)d_in[1];
    const int E = in_sizes[1] / 2;
    const int n = in_sizes[0] / DIMF;
    const int* src = ei;
    const int* dst = ei + E;
    const float* W0 = (const float*)d_in[3];  const float* b0 = (const float*)d_in[4];
    const float* W1 = (const float*)d_in[5];  const float* b1 = (const float*)d_in[6];
    const float* W2 = (const float*)d_in[7];  const float* b2 = (const float*)d_in[8];
    const float* Wp1 = (const float*)d_in[9];  const float* bp1 = (const float*)d_in[10];
    const float* Wp2 = (const float*)d_in[11]; const float* bp2 = (const float*)d_in[12];
    float* out = (float*)d_out;

    const int NBK = (n + 511) >> BSH;          // node buckets (<= 256)
    const int NBS = (E + 2047) >> ESH;         // edge_scatter blocks

    // Workspace (ALL arrays 256B-aligned; hp tables have n+1 rows, row n is
    // the zero row for clamped gather slots):
    //   gcursor[256] | row_start[n+1] | dinv[n] | csr_src[E] |
    //   hpA[(n+1)*64 bf16] | hpB[(n+1)*64 bf16]
    //   (ebuf = NBK fixed-CAP regions aliases hpB; dead once K1 writes hpB)
#define ALIGN256(q) (char*)(((size_t)(q) + 255) & ~(size_t)255)
    char* p = (char*)d_ws;
    int* gcursor      = (int*)p;              p += 256 * 4;
    p = ALIGN256(p);
    int* row_start    = (int*)p;              p += (size_t)(n + 1) * 4;
    p = ALIGN256(p);
    float* dinv       = (float*)p;            p += (size_t)n * 4;
    p = ALIGN256(p);
    int* csr_src      = (int*)p;              p += (size_t)E * 4;
    p = ALIGN256(p);
    __hip_bfloat16* hpA = (__hip_bfloat16*)p; p += (size_t)(n + 1) * DIMF * 2;
    p = ALIGN256(p);
    __hip_bfloat16* hpB = (__hip_bfloat16*)p;
    unsigned int* ebuf  = (unsigned int*)hpB;  // NBK*ECAP*4 <= (n+1)*128 B

    const int nblk32 = (n + 31) / 32;
    const int nblk64 = (n + 63) / 64;

    // --- CSR build (2 kernels + memset) ---
    hipMemsetAsync(gcursor, 0, 256 * 4, stream);
    hipLaunchKernelGGL(edge_scatter, dim3(NBS), dim3(512), 0, stream,
                       src, dst, gcursor, ebuf, E);
    hipLaunchKernelGGL(bucket_csr,   dim3(NBK), dim3(512), 0, stream,
                       ebuf, gcursor, row_start, csr_src, dinv, n, E);

    // --- fused pipeline: K0, K1, K2, K3 ---
    hipLaunchKernelGGL(gemm_scale_f32, dim3(nblk32), dim3(256), 0, stream,
                       x, W0, dinv, hpA, n);
    hipLaunchKernelGGL(gather_gemm, dim3(nblk64), dim3(512), 0, stream,
                       (const unsigned int*)hpA, row_start, csr_src, dinv, b0,
                       W1, hpB, n);
    hipLaunchKernelGGL(gather_gemm, dim3(nblk64), dim3(512), 0, stream,
                       (const unsigned int*)hpB, row_start, csr_src, dinv, b1,
                       W2, hpA, n);
    hipLaunchKernelGGL(gather_head, dim3(nblk64), dim3(512), 0, stream,
                       (const unsigned int*)hpA, row_start, csr_src, dinv, b2,
                       Wp1, bp1, Wp2, bp2, out, n);
}

// Round 15
// 268.237 us; speedup vs baseline: 1.0293x; 1.0293x over previous
//
#include <hip/hip_runtime.h>
#include <hip/hip_bf16.h>
#include <math.h>

// GCN stack: 3x [GCNConv + ReLU] + MLP head (64->32 relu ->40) + log_softmax.
// R29: disentangle R28's двух-variable change. edge_scatter: ESH back to 13
// (196 blocks, 42-edge write runs per bucket = coalesced, 50K gcursor
// atomics) but KEEP 512 threads (grid is block-count-limited at <1 block/CU,
// so threads/block is the only TLP lever there; 8 waves > 4). R28's ESH=11
// cost ~3x write amplification + 4x contended atomics (non-gather pool
// 100 -> 130us same-clock). Everything else byte-identical to R28/R27.

#define DIMF 64
#define BSH  9       // 512 nodes per bucket
#define ESH  13      // 8192 edges per scatter block
#define ECAP 16320   // fixed ebuf capacity per bucket (196*16320*4 <= hpB)
#define LSCAP 10240  // bucket_csr LDS staging capacity (40 KB)

static __device__ __forceinline__ unsigned short f2bf(float f)
{
    __hip_bfloat16 b = __float2bfloat16(f);
    return *(unsigned short*)&b;
}

// ---------------- CSR build: fused scatter ----------------

__global__ __launch_bounds__(512) void edge_scatter(
    const int* __restrict__ src, const int* __restrict__ dst,
    int* __restrict__ gcursor, unsigned int* __restrict__ ebuf, int E)
{
    __shared__ unsigned int  pk[8192];   // 32 KB packed (src<<9)|(dst&511)
    __shared__ unsigned char bk[8192];   // 8 KB bucket id (<=195)
    __shared__ int hcnt[256];
    __shared__ int hbase[256];
    int t = threadIdx.x;
    if (t < 256) hcnt[t] = 0;
    __syncthreads();
    int e0 = blockIdx.x << ESH;
    int e1 = min(E, e0 + 8192);
    int m = e1 - e0;
    for (int i = t; i < m; i += 512) {
        int d = dst[e0 + i];
        int s = src[e0 + i];
        int b = d >> BSH;
        pk[i] = ((unsigned int)s << BSH) | (unsigned int)(d & 511);
        bk[i] = (unsigned char)b;
        atomicAdd(&hcnt[b], 1);
    }
    __syncthreads();
    if (t < 256) {
        hbase[t] = hcnt[t] ? atomicAdd(&gcursor[t], hcnt[t]) : 0;
        hcnt[t] = 0;
    }
    __syncthreads();
    for (int i = t; i < m; i += 512) {
        int b = bk[i];
        int p = hbase[b] + atomicAdd(&hcnt[b], 1);
        ebuf[(size_t)b * ECAP + p] = pk[i];
    }
}

// ---------------- bucket_csr: 512 thr, LDS-staged compact list ----------

__global__ __launch_bounds__(512) void bucket_csr(
    const unsigned int* __restrict__ ebuf, const int* __restrict__ gcursor,
    int* __restrict__ row_start, int* __restrict__ csr_src,
    float* __restrict__ dinv, int n, int E)
{
    __shared__ int cnt[512];     // 2 KB: per-node count -> scan -> cursor
    __shared__ int ps[256];      // 1 KB: bucket-prefix scan
    __shared__ int ls[LSCAP];    // 40 KB: compact src staging
    int t = threadIdx.x;
    int blk = blockIdx.x;
    int node0 = blk << BSH;
    int nbk = gridDim.x;

    // exclusive prefix of bucket counts (first 256 threads; nbk <= 256)
    if (t < 256) ps[t] = (t < nbk) ? gcursor[t] : 0;
    __syncthreads();
    for (int off = 1; off < 256; off <<= 1) {
        int v = 0;
        if (t < 256 && t >= off) v = ps[t - off];
        __syncthreads();
        if (t < 256) ps[t] += v;
        __syncthreads();
    }
    int bs   = ps[blk] - gcursor[blk];   // global base of this bucket
    int bcnt = gcursor[blk];             // edges in this bucket

    // per-node histogram
    cnt[t] = 0;
    __syncthreads();
    size_t base = (size_t)blk * ECAP;
    for (int i = t; i < bcnt; i += 512)
        atomicAdd(&cnt[ebuf[base + i] & 511], 1);
    __syncthreads();
    int myc = cnt[t];
    __syncthreads();
    // inclusive scan over 512 node counts (512 threads, Hillis-Steele)
    for (int off = 1; off < 512; off <<= 1) {
        int v = (t >= off) ? cnt[t - off] : 0;
        __syncthreads();
        cnt[t] += v;
        __syncthreads();
    }
    int excl = cnt[t] - myc;
    int g = node0 + t;
    if (g < n) { row_start[g] = bs + excl; dinv[g] = rsqrtf((float)myc + 1.0f); }
    __syncthreads();
    cnt[t] = excl;                       // becomes local cursor
    __syncthreads();

    if (bcnt <= LSCAP) {
        // scatter into LDS staging (random 4B writes stay on-chip)
        for (int i = t; i < bcnt; i += 512) {
            unsigned int pkv = ebuf[base + i];
            int p = atomicAdd(&cnt[pkv & 511], 1);
            ls[p] = (int)(pkv >> BSH);
        }
        __syncthreads();
        // coalesced stream-out
        for (int i = t; i < bcnt; i += 512)
            csr_src[bs + i] = ls[i];
    } else {
        // fallback (statistically unreachable): direct global scatter
        for (int i = t; i < bcnt; i += 512) {
            unsigned int pkv = ebuf[base + i];
            int p = bs + atomicAdd(&cnt[pkv & 511], 1);
            csr_src[p] = (int)(pkv >> BSH);
        }
    }
    if (blk == gridDim.x - 1 && t == 0) row_start[n] = E;
}

// ---------------- shared register-blocked gemm body ----------------

#define GEMM_RB(ACC0, ACC1, XS, WS)                                        \
    float ACC0[4] = {0.f, 0.f, 0.f, 0.f};                                  \
    float ACC1[4] = {0.f, 0.f, 0.f, 0.f};                                  \
    {                                                                      \
        int cg4 = (t & 15) << 2;                                           \
        int rr0 = (t >> 4) << 1;                                           \
        _Pragma("unroll 4")                                                \
        for (int k = 0; k < 64; k++) {                                     \
            float4 w = *(const float4*)&WS[(k << 6) + cg4];                \
            float x0 = XS[rr0][k];                                         \
            float x1 = XS[rr0 + 1][k];                                     \
            ACC0[0] = fmaf(x0, w.x, ACC0[0]);                              \
            ACC0[1] = fmaf(x0, w.y, ACC0[1]);                              \
            ACC0[2] = fmaf(x0, w.z, ACC0[2]);                              \
            ACC0[3] = fmaf(x0, w.w, ACC0[3]);                              \
            ACC1[0] = fmaf(x1, w.x, ACC1[0]);                              \
            ACC1[1] = fmaf(x1, w.y, ACC1[1]);                              \
            ACC1[2] = fmaf(x1, w.z, ACC1[2]);                              \
            ACC1[3] = fmaf(x1, w.w, ACC1[3]);                              \
        }                                                                  \
    }

#define GEMM_STORE(ACC, GR)                                                \
    if ((GR) < n) {                                                        \
        float dv = dinv[GR];                                               \
        ushort4 u;                                                         \
        u.x = f2bf(ACC[0] * dv);                                           \
        u.y = f2bf(ACC[1] * dv);                                           \
        u.z = f2bf(ACC[2] * dv);                                           \
        u.w = f2bf(ACC[3] * dv);                                           \
        *(ushort4*)(hpout + (size_t)(GR) * DIMF + ((t & 15) << 2)) = u;    \
    }

// Write the zero row at hp[n] (gather clamps out-of-degree slots here).
#define ZERO_ROW(HP)                                                       \
    if (blockIdx.x == 0 && t < 32)                                         \
        ((unsigned int*)(HP))[(size_t)n * 32 + t] = 0u;

// ---------------- K0: gemm0 (f32 x -> hpA bf16), 256 threads ----------

__global__ __launch_bounds__(256) void gemm_scale_f32(
    const float* __restrict__ xin, const float* __restrict__ W,
    const float* __restrict__ dinv, __hip_bfloat16* __restrict__ hpout, int n)
{
    __shared__ float Ws[64 * 64];
    __shared__ float Xs[32][65];
    int t = threadIdx.x;
    ZERO_ROW(hpout)
    {
        const float4* Wv = (const float4*)W;
        float4* Wsv = (float4*)Ws;
        for (int i = t; i < 1024; i += 256) Wsv[i] = Wv[i];
    }
    int row0 = blockIdx.x * 32;
    for (int i = t; i < 512; i += 256) {
        int r = i >> 4, c4 = (i & 15) << 2;
        int gr = row0 + r;
        float4 v = {0.f, 0.f, 0.f, 0.f};
        if (gr < n) v = *(const float4*)(xin + (size_t)gr * DIMF + c4);
        Xs[r][c4]     = v.x;
        Xs[r][c4 + 1] = v.y;
        Xs[r][c4 + 2] = v.z;
        Xs[r][c4 + 3] = v.w;
    }
    __syncthreads();

    GEMM_RB(acc0, acc1, Xs, Ws)
    int gr0 = row0 + ((t >> 4) << 1);
    GEMM_STORE(acc0, gr0)
    GEMM_STORE(acc1, gr0 + 1)
}

// ---------------- shared gather body (8-deep, vectorized indices) --------
// Lane o of each 8-lane group loads ONE index csr_src[rs+k+o] (clamped to
// the zero row n for slots >= deg); __shfl within the group broadcasts the
// 8 indices for the 8 row loads. Row j -> a[j%4] striping preserved.

#define ADDROW(a, v)                                                       \
    {                                                                      \
        a[0] += __uint_as_float((v).x << 16);                              \
        a[1] += __uint_as_float((v).x & 0xffff0000u);                      \
        a[2] += __uint_as_float((v).y << 16);                              \
        a[3] += __uint_as_float((v).y & 0xffff0000u);                      \
        a[4] += __uint_as_float((v).z << 16);                              \
        a[5] += __uint_as_float((v).z & 0xffff0000u);                      \
        a[6] += __uint_as_float((v).w << 16);                              \
        a[7] += __uint_as_float((v).w & 0xffff0000u);                      \
    }

#define GATHER_BODY(xv_out)                                                    \
    float xv_out[8];                                                           \
    {                                                                          \
        int rs = row_start[node];                                              \
        int deg = row_start[node + 1] - rs;                                    \
        float a0[8], a1[8], a2[8], a3[8];                                      \
        _Pragma("unroll")                                                      \
        for (int i = 0; i < 8; i++) { a0[i]=0.f; a1[i]=0.f; a2[i]=0.f; a3[i]=0.f; } \
        {                                                                      \
            uint4 v = *(const uint4*)(hprime + (size_t)node * 32 + uoff);      \
            ADDROW(a0, v);                                                     \
        }                                                                      \
        int gb = lane & ~7;            /* group base lane in wave */           \
        int idxv;                                                              \
        {                                                                      \
            int _c = csr_src[rs + o];                                          \
            idxv = (o < deg) ? _c : n;                                         \
        }                                                                      \
        for (int k = 0; k < deg; k += 8) {                                     \
            int i0 = __shfl(idxv, gb + 0, 64);                                 \
            int i1 = __shfl(idxv, gb + 1, 64);                                 \
            int i2 = __shfl(idxv, gb + 2, 64);                                 \
            int i3 = __shfl(idxv, gb + 3, 64);                                 \
            int i4 = __shfl(idxv, gb + 4, 64);                                 \
            int i5 = __shfl(idxv, gb + 5, 64);                                 \
            int i6 = __shfl(idxv, gb + 6, 64);                                 \
            int i7 = __shfl(idxv, gb + 7, 64);                                 \
            int kn = k + 8;                                                    \
            int _c = csr_src[rs + kn + o];                                     \
            int nidx = (kn + o < deg) ? _c : n;                                \
            uint4 v0 = *(const uint4*)(hprime + (size_t)i0 * 32 + uoff);       \
            uint4 v1 = *(const uint4*)(hprime + (size_t)i1 * 32 + uoff);       \
            uint4 v2 = *(const uint4*)(hprime + (size_t)i2 * 32 + uoff);       \
            uint4 v3 = *(const uint4*)(hprime + (size_t)i3 * 32 + uoff);       \
            uint4 v4 = *(const uint4*)(hprime + (size_t)i4 * 32 + uoff);       \
            uint4 v5 = *(const uint4*)(hprime + (size_t)i5 * 32 + uoff);       \
            uint4 v6 = *(const uint4*)(hprime + (size_t)i6 * 32 + uoff);       \
            uint4 v7 = *(const uint4*)(hprime + (size_t)i7 * 32 + uoff);       \
            ADDROW(a0, v0); ADDROW(a1, v1); ADDROW(a2, v2); ADDROW(a3, v3);    \
            ADDROW(a0, v4); ADDROW(a1, v5); ADDROW(a2, v6); ADDROW(a3, v7);    \
            idxv = nidx;                                                       \
        }                                                                      \
        int f8 = uoff << 1;                                                    \
        float dv = dinv[node];                                                 \
        _Pragma("unroll")                                                      \
        for (int j = 0; j < 8; j++)                                            \
            xv_out[j] = fmaxf(fmaf(dv, a0[j] + a1[j] + a2[j] + a3[j],          \
                                   b[f8 + j]), 0.0f);                          \
    }

// ---------------- K1/K2: gather(l) + gemm(l+1), 512 thr / 64 nodes -------

__global__ __launch_bounds__(512) void gather_gemm(
    const unsigned int* __restrict__ hprime,  // hp(l) bf16x2, 32 uints/row
    const int* __restrict__ row_start, const int* __restrict__ csr_src,
    const float* __restrict__ dinv, const float* __restrict__ b,   // b(l)
    const float* __restrict__ Wn,                                  // W(l+1)
    __hip_bfloat16* __restrict__ hpout, int n)
{
    __shared__ float Ws[64 * 64];   // 16 KB
    __shared__ float Xs[64][65];    // 16.6 KB
    int t = threadIdx.x;
    ZERO_ROW(hpout)
    {
        const float4* Wv = (const float4*)Wn;
        float4* Wsv = (float4*)Ws;
        for (int i = t; i < 1024; i += 512) Wsv[i] = Wv[i];
    }

    int wave = t >> 6;
    int lane = t & 63;
    int slot = lane >> 3;
    int o    = lane & 7;
    int uoff = o << 2;
    int ln   = (wave << 3) + slot;          // local node 0..63
    int row0 = blockIdx.x * 64;
    int node = row0 + ln;
    int f8l  = o << 3;

    if (node < n) {
        GATHER_BODY(xv)
#pragma unroll
        for (int j = 0; j < 8; j++) Xs[ln][f8l + j] = xv[j];
    } else {
#pragma unroll
        for (int j = 0; j < 8; j++) Xs[ln][f8l + j] = 0.0f;
    }
    __syncthreads();

    GEMM_RB(acc0, acc1, Xs, Ws)
    int gr0 = row0 + ((t >> 4) << 1);
    GEMM_STORE(acc0, gr0)
    GEMM_STORE(acc1, gr0 + 1)
}

// ---------------- K3: gather(2) + MLP head, 512 thr / 64 nodes ----------

__global__ __launch_bounds__(512) void gather_head(
    const unsigned int* __restrict__ hprime,  // hp(2) bf16x2
    const int* __restrict__ row_start, const int* __restrict__ csr_src,
    const float* __restrict__ dinv, const float* __restrict__ b,   // b(2)
    const float* __restrict__ Wp1, const float* __restrict__ bp1,
    const float* __restrict__ Wp2, const float* __restrict__ bp2,
    float* __restrict__ out, int n)
{
    __shared__ float W1s[64 * 32];   // 8 KB
    __shared__ float W2t[40][36];    // 5.76 KB, transposed + padded
    __shared__ float b1s[32], b2s[40];
    __shared__ float Xs[64][65];     // 16.6 KB
    __shared__ float Hs[64][33];     // 8.4 KB
    int t = threadIdx.x;
    {
        const float4* Wv = (const float4*)Wp1;
        float4* Wsv = (float4*)W1s;
        for (int i = t; i < 512; i += 512) Wsv[i] = Wv[i];
    }
    for (int i = t; i < 1280; i += 512) {
        int k = i & 31, j = i >> 5;
        W2t[j][k] = Wp2[k * 40 + j];
    }
    if (t < 32) b1s[t] = bp1[t];
    if (t < 40) b2s[t] = bp2[t];

    int wave = t >> 6;
    int lane = t & 63;
    int slot = lane >> 3;
    int o    = lane & 7;
    int uoff = o << 2;
    int ln   = (wave << 3) + slot;          // local node 0..63
    int node = blockIdx.x * 64 + ln;
    int f8l  = o << 3;

    if (node < n) {
        GATHER_BODY(xv)
#pragma unroll
        for (int j = 0; j < 8; j++) Xs[ln][f8l + j] = xv[j];
    } else {
#pragma unroll
        for (int j = 0; j < 8; j++) Xs[ln][f8l + j] = 0.0f;
    }
    __syncthreads();   // Xs complete + weights staged

    // lane computes h channels o*4 .. o*4+3 over all 64 inputs
    float h[4];
#pragma unroll
    for (int m = 0; m < 4; m++) h[m] = b1s[o * 4 + m];
#pragma unroll 4
    for (int k = 0; k < 64; k++) {
        float xk = Xs[ln][k];
        float4 w = *(const float4*)&W1s[(k << 5) + (o << 2)];
        h[0] = fmaf(xk, w.x, h[0]);
        h[1] = fmaf(xk, w.y, h[1]);
        h[2] = fmaf(xk, w.z, h[2]);
        h[3] = fmaf(xk, w.w, h[3]);
    }
#pragma unroll
    for (int m = 0; m < 4; m++) Hs[ln][o * 4 + m] = fmaxf(h[m], 0.0f);
    // Hs written/read by the same wave: no __syncthreads needed

    if (node < n) {
        float oo[5];
#pragma unroll
        for (int m = 0; m < 5; m++) oo[m] = b2s[o * 5 + m];
#pragma unroll
        for (int k4 = 0; k4 < 8; k4++) {
            float hk0 = Hs[ln][4 * k4 + 0];
            float hk1 = Hs[ln][4 * k4 + 1];
            float hk2 = Hs[ln][4 * k4 + 2];
            float hk3 = Hs[ln][4 * k4 + 3];
#pragma unroll
            for (int m = 0; m < 5; m++) {
                float4 w = *(const float4*)&W2t[o * 5 + m][4 * k4];
                oo[m] = fmaf(hk3, w.w, fmaf(hk2, w.z,
                         fmaf(hk1, w.y, fmaf(hk0, w.x, oo[m]))));
            }
        }
        float mx = oo[0];
#pragma unroll
        for (int m = 1; m < 5; m++) mx = fmaxf(mx, oo[m]);
#pragma unroll
        for (int mask = 1; mask <= 4; mask <<= 1) mx = fmaxf(mx, __shfl_xor(mx, mask));
        float se = 0.0f;
#pragma unroll
        for (int m = 0; m < 5; m++) se += expf(oo[m] - mx);
#pragma unroll
        for (int mask = 1; mask <= 4; mask <<= 1) se += __shfl_xor(se, mask);
        float lse = logf(se) + mx;
        float* op = out + (size_t)node * 40 + o * 5;
#pragma unroll
        for (int m = 0; m < 5; m++) op[m] = oo[m] - lse;
    }
}

extern "C" void kernel_launch(void* const* d_in, const int* in_sizes, int n_in,
                              void* d_out, int out_size, void* d_ws, size_t ws_size,
                              hipStream_t stream)
{
    const float* x  = (const float*)d_in[0];
    const int*   ei = (const int*)d_in[1];
    const int E = in_sizes[1] / 2;
    const int n = in_sizes[0] / DIMF;
    const int* src = ei;
    const int* dst = ei + E;
    const float* W0 = (const float*)d_in[3];  const float* b0 = (const float*)d_in[4];
    const float* W1 = (const float*)d_in[5];  const float* b1 = (const float*)d_in[6];
    const float* W2 = (const float*)d_in[7];  const float* b2 = (const float*)d_in[8];
    const float* Wp1 = (const float*)d_in[9];  const float* bp1 = (const float*)d_in[10];
    const float* Wp2 = (const float*)d_in[11]; const float* bp2 = (const float*)d_in[12];
    float* out = (float*)d_out;

    const int NBK = (n + 511) >> BSH;          // node buckets (<= 256)
    const int NBS = (E + 8191) >> ESH;         // edge_scatter blocks

    // Workspace (ALL arrays 256B-aligned; hp tables have n+1 rows, row n is
    // the zero row for clamped gather slots):
    //   gcursor[256] | row_start[n+1] | dinv[n] | csr_src[E] |
    //   hpA[(n+1)*64 bf16] | hpB[(n+1)*64 bf16]
    //   (ebuf = NBK fixed-CAP regions aliases hpB; dead once K1 writes hpB)
#define ALIGN256(q) (char*)(((size_t)(q) + 255) & ~(size_t)255)
    char* p = (char*)d_ws;
    int* gcursor      = (int*)p;              p += 256 * 4;
    p = ALIGN256(p);
    int* row_start    = (int*)p;              p += (size_t)(n + 1) * 4;
    p = ALIGN256(p);
    float* dinv       = (float*)p;            p += (size_t)n * 4;
    p = ALIGN256(p);
    int* csr_src      = (int*)p;              p += (size_t)E * 4;
    p = ALIGN256(p);
    __hip_bfloat16* hpA = (__hip_bfloat16*)p; p += (size_t)(n + 1) * DIMF * 2;
    p = ALIGN256(p);
    __hip_bfloat16* hpB = (__hip_bfloat16*)p;
    unsigned int* ebuf  = (unsigned int*)hpB;  // NBK*ECAP*4 <= (n+1)*128 B

    const int nblk32 = (n + 31) / 32;
    const int nblk64 = (n + 63) / 64;

    // --- CSR build (2 kernels + memset) ---
    hipMemsetAsync(gcursor, 0, 256 * 4, stream);
    hipLaunchKernelGGL(edge_scatter, dim3(NBS), dim3(512), 0, stream,
                       src, dst, gcursor, ebuf, E);
    hipLaunchKernelGGL(bucket_csr,   dim3(NBK), dim3(512), 0, stream,
                       ebuf, gcursor, row_start, csr_src, dinv, n, E);

    // --- fused pipeline: K0, K1, K2, K3 ---
    hipLaunchKernelGGL(gemm_scale_f32, dim3(nblk32), dim3(256), 0, stream,
                       x, W0, dinv, hpA, n);
    hipLaunchKernelGGL(gather_gemm, dim3(nblk64), dim3(512), 0, stream,
                       (const unsigned int*)hpA, row_start, csr_src, dinv, b0,
                       W1, hpB, n);
    hipLaunchKernelGGL(gather_gemm, dim3(nblk64), dim3(512), 0, stream,
                       (const unsigned int*)hpB, row_start, csr_src, dinv, b1,
                       W2, hpA, n);
    hipLaunchKernelGGL(gather_head, dim3(nblk64), dim3(512), 0, stream,
                       (const unsigned int*)hpA, row_start, csr_src, dinv, b2,
                       Wp1, bp1, Wp2, bp2, out, n);
}